// Round 2
// 216.068 us; speedup vs baseline: 1.0846x; 1.0846x over previous
//
#include <hip/hip_runtime.h>
#include <hip/hip_bf16.h>

typedef __hip_bfloat16 bf16;
typedef __bf16 bfx8 __attribute__((ext_vector_type(8)));
typedef float f32x4 __attribute__((ext_vector_type(4)));

#define BM 128

typedef __attribute__((address_space(3))) void lds_void_t;
typedef const __attribute__((address_space(1))) void gbl_void_t;

// ---------------------------------------------------------------------------
// Fused prep: HT[e][n] = bf16(H[n][e]); de[e] += colsum; dvr[n] += row.w
// (Hb is produced post-K4 by transpose_kernel so d_out can hold K4 slices.)
__global__ void prep_kernel(const float* __restrict__ H, const float* __restrict__ w,
                            bf16* __restrict__ HT,
                            float* __restrict__ de, float* __restrict__ dvr, int N, int E) {
    __shared__ bf16 tile[64][65];
    __shared__ float cred[4][64];
    __shared__ float rred[4][64];
    int eb = blockIdx.x * 64, nb = blockIdx.y * 64;
    int tid = threadIdx.x;
    int c = tid & 63, g = tid >> 6;

    float cs = 0.f;
#pragma unroll
    for (int k = 0; k < 16; k++) {
        int r = g + (k << 2);
        float v = H[(size_t)(nb + r) * E + eb + c];
        bf16 bv = __float2bfloat16(v);
        tile[r][c] = bv;
        cs += v;
    }
    cred[g][c] = cs;
    __syncthreads();
    if (g == 0) {
        float s = cred[0][c] + cred[1][c] + cred[2][c] + cred[3][c];
        atomicAdd(&de[eb + c], s);
    }
    float rs = 0.f;
#pragma unroll
    for (int k = 0; k < 16; k++) {
        int cc = g + (k << 2);
        rs += __bfloat162float(tile[c][cc]) * w[eb + cc];
    }
    rred[g][c] = rs;
    __syncthreads();
    if (g == 1) {
        float s = rred[0][c] + rred[1][c] + rred[2][c] + rred[3][c];
        atomicAdd(&dvr[nb + c], s);
    }
#pragma unroll
    for (int k = 0; k < 16; k++) {
        int r = g + (k << 2);
        HT[(size_t)(eb + r) * N + nb + c] = tile[c][r];  // transposed (coalesced in n)
    }
}

__global__ void finalize_kernel(const float* __restrict__ dvr, const float* __restrict__ de,
                                const float* __restrict__ w, float* __restrict__ dv_is,
                                float* __restrict__ wsc, int N, int E) {
    int i = blockIdx.x * 256 + threadIdx.x;
    if (i < N) dv_is[i] = rsqrtf(dvr[i] + 1e-8f);
    if (i < E) wsc[i] = w[i] / (de[i] + 1e-8f);
}

// ---------------------------------------------------------------------------
// Sync-staged conv GEMM (K3): both operands f32, convert while staging.
// xs_t[bf16] = (acc + rvec[row]) * cvec[col]
__global__ __launch_bounds__(256) void gemm_bt_conv(
    const float* __restrict__ A, const float* __restrict__ B, int K,
    bf16* __restrict__ C, int ldc,
    const float* __restrict__ rvec, const float* __restrict__ cvec,
    long long bStride, long long cStride) {
    __shared__ __align__(16) bf16 As[BM * 40];
    __shared__ __align__(16) bf16 Bs[BM * 40];

    const float* Bp = B + (size_t)blockIdx.z * (size_t)bStride;
    bf16*        Cp = C + (size_t)blockIdx.z * (size_t)cStride;

    const int tid     = threadIdx.x;
    const int rowBase = blockIdx.y * BM;
    const int colBase = blockIdx.x * BM;
    const int wave = tid >> 6, lane = tid & 63;
    const int wr = (wave >> 1) * 64;
    const int wc = (wave & 1) * 64;
    const int lcol = lane & 15, quad = lane >> 4;

    f32x4 acc[4][4];
#pragma unroll
    for (int i = 0; i < 4; i++)
#pragma unroll
        for (int j = 0; j < 4; j++) acc[i][j] = (f32x4){0.f, 0.f, 0.f, 0.f};

    for (int k0 = 0; k0 < K; k0 += 32) {
#pragma unroll
        for (int c = 0; c < 2; c++) {
            int ch = tid + c * 256;
            int r = ch >> 2, kc = (ch & 3) << 3;
            size_t aoff = (size_t)(rowBase + r) * K + k0 + kc;
            size_t boff = (size_t)(colBase + r) * K + k0 + kc;
            f32x4 p0 = *(const f32x4*)&A[aoff];
            f32x4 p1 = *(const f32x4*)&A[aoff + 4];
            bfx8 va;
#pragma unroll
            for (int t = 0; t < 4; t++) { va[t] = (__bf16)p0[t]; va[4 + t] = (__bf16)p1[t]; }
            *(bfx8*)&As[r * 40 + kc] = va;
            f32x4 q0 = *(const f32x4*)&Bp[boff];
            f32x4 q1 = *(const f32x4*)&Bp[boff + 4];
            bfx8 vb;
#pragma unroll
            for (int t = 0; t < 4; t++) { vb[t] = (__bf16)q0[t]; vb[4 + t] = (__bf16)q1[t]; }
            *(bfx8*)&Bs[r * 40 + kc] = vb;
        }
        __syncthreads();

        bfx8 af[4], bfr[4];
#pragma unroll
        for (int i = 0; i < 4; i++)
            af[i] = *(const bfx8*)&As[(wr + i * 16 + lcol) * 40 + quad * 8];
#pragma unroll
        for (int j = 0; j < 4; j++)
            bfr[j] = *(const bfx8*)&Bs[(wc + j * 16 + lcol) * 40 + quad * 8];
#pragma unroll
        for (int i = 0; i < 4; i++)
#pragma unroll
            for (int j = 0; j < 4; j++)
                acc[i][j] = __builtin_amdgcn_mfma_f32_16x16x32_bf16(af[i], bfr[j], acc[i][j], 0, 0, 0);
        __syncthreads();
    }

#pragma unroll
    for (int i = 0; i < 4; i++) {
#pragma unroll
        for (int j = 0; j < 4; j++) {
#pragma unroll
            for (int r = 0; r < 4; r++) {
                int grow = rowBase + wr + i * 16 + quad * 4 + r;
                int gcol = colBase + wc + j * 16 + lcol;
                float v = (acc[i][j][r] + rvec[grow]) * cvec[gcol];
                Cp[(size_t)grow * ldc + gcol] = __float2bfloat16(v);
            }
        }
    }
}

// ---------------------------------------------------------------------------
// 256x256 8-phase GEMM (T1+T2+T3+T4+T5), BK=64, 8 waves (2Mx4N), 512 thr.
// B^T form: C[row][col] = sum_k A[row][k]*Bt[col][k].  Split-K via blockIdx.z
// (kLen per slice), slice bz -> S{0..3}, plain bf16 [row][ldc] store.
// LDS 128 KiB: [A|B] x [buf0|buf1] x [half0|half1] x (128 rows x 64 k) bf16.
// XOR swizzle (involution, both sides): 16B-slot s of row r holds global
// slot s^(r&7)  -> per quarter-wave all 8 slots distinct (2 lanes/slot = free
// per m136); global_load_lds dest stays linear, source pre-swizzled (rule 21).
// Stage rotation per K-tile u (phases P1..P4): P1:A0(u+1) P2:A1(u+1)
// P3:B0(u+2) P4:B1(u+2); vmcnt(4) once per K-tile at P4 (never 0 in loop).
// Safety: B(u) reads are register-resident before P2's end barrier (MFMA
// forces lgkmcnt) -> B(u+2) stage into same region at P3 is safe; A(u+1)
// goes to the opposite buffer.

#define STG_A(cb, h, u) do { \
    __builtin_amdgcn_global_load_lds((gbl_void_t*)(ga##h##0 + (size_t)(u) * 64), \
        (lds_void_t*)&SM[(cb) * 16384 + (h) * 8192 + dOff], 16, 0, 0); \
    __builtin_amdgcn_global_load_lds((gbl_void_t*)(ga##h##1 + (size_t)(u) * 64), \
        (lds_void_t*)&SM[(cb) * 16384 + (h) * 8192 + 4096 + dOff], 16, 0, 0); \
} while (0)

#define STG_B(cb, h, u) do { \
    __builtin_amdgcn_global_load_lds((gbl_void_t*)(gb##h##0 + (size_t)(u) * 64), \
        (lds_void_t*)&SM[32768 + (cb) * 16384 + (h) * 8192 + dOff], 16, 0, 0); \
    __builtin_amdgcn_global_load_lds((gbl_void_t*)(gb##h##1 + (size_t)(u) * 64), \
        (lds_void_t*)&SM[32768 + (cb) * 16384 + (h) * 8192 + 4096 + dOff], 16, 0, 0); \
} while (0)

#define LDA_(cb, qi, i, kk) \
    (*(const bfx8*)&SM[(cb) * 16384 + aBase + ((qi) * 64 + (i) * 16) * 64 + ra##kk])
#define LDB_(cb, j, kk) \
    (*(const bfx8*)&SM[32768 + (cb) * 16384 + bjb[j] + ra##kk])

#define PH_MFMA(I0, J0) do { \
    __builtin_amdgcn_s_setprio(1); \
    _Pragma("unroll") \
    for (int i_ = 0; i_ < 4; i_++) { \
        _Pragma("unroll") \
        for (int jj_ = 0; jj_ < 2; jj_++) { \
            acc[(I0) + i_][(J0) + jj_] = __builtin_amdgcn_mfma_f32_16x16x32_bf16( \
                af[i_][0], bf[(J0) + jj_][0], acc[(I0) + i_][(J0) + jj_], 0, 0, 0); \
            acc[(I0) + i_][(J0) + jj_] = __builtin_amdgcn_mfma_f32_16x16x32_bf16( \
                af[i_][1], bf[(J0) + jj_][1], acc[(I0) + i_][(J0) + jj_], 0, 0, 0); \
        } \
    } \
    __builtin_amdgcn_s_setprio(0); \
} while (0)

#define KTILE(cb, uA, uB) do { \
    /* P1: A-quad0 + B j01 reads, stage A0(next) */ \
    _Pragma("unroll") \
    for (int i_ = 0; i_ < 4; i_++) { af[i_][0] = LDA_(cb, 0, i_, 0); af[i_][1] = LDA_(cb, 0, i_, 1); } \
    _Pragma("unroll") \
    for (int j_ = 0; j_ < 2; j_++) { bf[j_][0] = LDB_(cb, j_, 0); bf[j_][1] = LDB_(cb, j_, 1); } \
    STG_A((cb) ^ 1, 0, uA); \
    __builtin_amdgcn_s_barrier(); \
    PH_MFMA(0, 0); \
    __builtin_amdgcn_s_barrier(); \
    /* P2: B j23 reads, stage A1(next) */ \
    _Pragma("unroll") \
    for (int j_ = 0; j_ < 2; j_++) { bf[2 + j_][0] = LDB_(cb, 2 + j_, 0); bf[2 + j_][1] = LDB_(cb, 2 + j_, 1); } \
    STG_A((cb) ^ 1, 1, uA); \
    __builtin_amdgcn_s_barrier(); \
    PH_MFMA(0, 2); \
    __builtin_amdgcn_s_barrier(); \
    /* P3: A-quad1 reads, stage B0(next-next) into current buf (B reads done) */ \
    _Pragma("unroll") \
    for (int i_ = 0; i_ < 4; i_++) { af[i_][0] = LDA_(cb, 1, i_, 0); af[i_][1] = LDA_(cb, 1, i_, 1); } \
    STG_B(cb, 0, uB); \
    __builtin_amdgcn_s_barrier(); \
    PH_MFMA(4, 2); \
    __builtin_amdgcn_s_barrier(); \
    /* P4: no reads, stage B1(next-next); counted vmcnt once per K-tile */ \
    STG_B(cb, 1, uB); \
    __builtin_amdgcn_s_barrier(); \
    PH_MFMA(4, 0); \
    asm volatile("s_waitcnt vmcnt(4)" ::: "memory"); \
    __builtin_amdgcn_s_barrier(); \
} while (0)

__global__ __launch_bounds__(512, 2) void gemm8ph(
    const bf16* __restrict__ A, const bf16* __restrict__ Bt, int Kst, int kLen,
    bf16* __restrict__ S0, bf16* __restrict__ S1, bf16* __restrict__ S2, bf16* __restrict__ S3,
    int ldc) {
    __shared__ __align__(16) bf16 SM[65536];  // 128 KiB

    // XCD-bijective swizzle (nwg % 8 == 0 for both launch shapes)
    const int nx = gridDim.x, ny = gridDim.y;
    const int nwg = nx * ny * gridDim.z;
    const int lin = (blockIdx.z * ny + blockIdx.y) * nx + blockIdx.x;
    const int cpx = nwg >> 3;
    const int swz = (lin & 7) * cpx + (lin >> 3);
    const int bx = swz % nx;
    const int t1 = swz / nx;
    const int by = t1 % ny;
    const int bz = t1 / ny;
    bf16* Cs = (bz == 0) ? S0 : (bz == 1) ? S1 : (bz == 2) ? S2 : S3;
    const int kBase = bz * kLen;
    const int NT = kLen >> 6;

    const int tid = threadIdx.x;
    const int lane = tid & 63, wave = tid >> 6;
    const int lcol = lane & 15, quad = lane >> 4;
    const int wr = (wave >> 2) * 128, wc = (wave & 3) * 64;
    const int aBase = (wave >> 2) * 8192;  // A half this wave reads
    const int xr = lcol & 7;               // read-side xor (== rowInHalf & 7)

    const int rowBase = by * 256, colBase = bx * 256;

    // fragment read offsets (bf16 elems): row*64 + (slot^xr)*8
    const int ra0 = lcol * 64 + ((quad ^ xr) << 3);
    const int ra1 = lcol * 64 + (((4 + quad) ^ xr) << 3);
    int bjb[4];
#pragma unroll
    for (int j = 0; j < 4; j++) {
        int rg = wc + j * 16;
        bjb[j] = ((rg >> 7) * 8192) + ((rg & 127) * 64);
    }

    // staging: thread t -> (row = t/8 + l*64, 16B-slot = t&7) per half-tile;
    // global source pre-swizzled: element col = (slot ^ (row&7))*8
    const int srow = tid >> 3, slot = tid & 7;
    const int r0 = srow, r1 = srow + 64;
    const int sx0 = (slot ^ (r0 & 7)) << 3;
    const int sx1 = (slot ^ (r1 & 7)) << 3;
    const bf16* ga00 = A + (size_t)(rowBase + r0) * Kst + kBase + sx0;
    const bf16* ga01 = A + (size_t)(rowBase + r1) * Kst + kBase + sx1;
    const bf16* ga10 = A + (size_t)(rowBase + 128 + r0) * Kst + kBase + sx0;
    const bf16* ga11 = A + (size_t)(rowBase + 128 + r1) * Kst + kBase + sx1;
    const bf16* gb00 = Bt + (size_t)(colBase + r0) * Kst + kBase + sx0;
    const bf16* gb01 = Bt + (size_t)(colBase + r1) * Kst + kBase + sx1;
    const bf16* gb10 = Bt + (size_t)(colBase + 128 + r0) * Kst + kBase + sx0;
    const bf16* gb11 = Bt + (size_t)(colBase + 128 + r1) * Kst + kBase + sx1;
    const int dOff = tid * 8;  // linear LDS dest (elems)

    f32x4 acc[8][4];
#pragma unroll
    for (int i = 0; i < 8; i++)
#pragma unroll
        for (int j = 0; j < 4; j++) acc[i][j] = (f32x4){0.f, 0.f, 0.f, 0.f};
    bfx8 af[4][2], bf[4][2];

    // prologue: A(0), B(0), B(1); allow B(1)'s 4 loads to stay in flight
    STG_A(0, 0, 0); STG_A(0, 1, 0); STG_B(0, 0, 0); STG_B(0, 1, 0);
    STG_B(1, 0, 1); STG_B(1, 1, 1);
    asm volatile("s_waitcnt vmcnt(4)" ::: "memory");
    __builtin_amdgcn_s_barrier();

    const int nPairs = NT >> 1;
    for (int it = 0; it < nPairs; ++it) {
        int u1 = 2 * it + 1;
        int u2 = 2 * it + 2; if (u2 > NT - 1) u2 = NT - 1;  // tail clamp: restage
        int u3 = 2 * it + 3; if (u3 > NT - 1) u3 = NT - 1;  // of identical bytes
        KTILE(0, u1, u2);
        KTILE(1, u2, u3);
    }

    // epilogue: C/D layout col=lane&15, row=quad*4+reg (verified m89/m91)
#pragma unroll
    for (int i = 0; i < 8; i++) {
#pragma unroll
        for (int j = 0; j < 4; j++) {
#pragma unroll
            for (int r = 0; r < 4; r++) {
                int grow = rowBase + wr + i * 16 + quad * 4 + r;
                int gcol = colBase + wc + j * 16 + lcol;
                Cs[(size_t)grow * ldc + gcol] = __float2bfloat16(acc[i][j][r]);
            }
        }
    }
}

// ---------------------------------------------------------------------------
// t_t[c][e] = bf16((s0+s1+s2+s3) * wsc[e]);  [2048][2048], 8 elems/thread
__global__ void combine4_kernel(const bf16* __restrict__ s0, const bf16* __restrict__ s1,
                                const bf16* __restrict__ s2, const bf16* __restrict__ s3,
                                const float* __restrict__ wsc, bf16* __restrict__ tt) {
    size_t i = ((size_t)blockIdx.x * 256 + threadIdx.x) * 8;
    int e = (int)(i & 2047);
    bfx8 a = *(const bfx8*)&s0[i];
    bfx8 b = *(const bfx8*)&s1[i];
    bfx8 c = *(const bfx8*)&s2[i];
    bfx8 d = *(const bfx8*)&s3[i];
    bfx8 v;
#pragma unroll
    for (int t = 0; t < 8; t++)
        v[t] = (__bf16)((((float)a[t] + (float)b[t]) + ((float)c[t] + (float)d[t])) * wsc[e + t]);
    *(bfx8*)&tt[i] = v;
}

// dst[C][R] = src[R][C]^T, 64x64 tiles (HT[e][n] -> Hb[n][e])
// LDS tile is __bf16 (NOT __hip_bfloat16: its operator= overload set makes
// __bf16 assignment ambiguous -> the round-1 compile error).
__global__ void transpose_kernel(const bf16* __restrict__ src, bf16* __restrict__ dst,
                                 int R, int C) {
    __shared__ __bf16 t[64][68];
    int cb = blockIdx.x * 64, rb = blockIdx.y * 64;
    int tid = threadIdx.x;
    int lc = tid & 7, lr = tid >> 3;  // 8 col-groups x 32 rows
#pragma unroll
    for (int p = 0; p < 2; p++) {
        int r = lr + p * 32;
        bfx8 v = *(const bfx8*)&src[(size_t)(rb + r) * C + cb + lc * 8];
#pragma unroll
        for (int q = 0; q < 8; q++) t[r][lc * 8 + q] = v[q];
    }
    __syncthreads();
#pragma unroll
    for (int p = 0; p < 2; p++) {
        int c = lr + p * 32;  // output row = source col
        bfx8 v;
#pragma unroll
        for (int q = 0; q < 8; q++) v[q] = t[lc * 8 + q][c];
        *(bfx8*)&dst[(size_t)(cb + c) * R + rb + lc * 8] = v;
    }
}

// out[b][n][o] = dv_is[n] * (sA[n][b*256+o] + sB[n][b*256+o])
__global__ void combine_out_kernel(const bf16* __restrict__ sA, const bf16* __restrict__ sB,
                                   const float* __restrict__ dv_is, float* __restrict__ out) {
    size_t t8 = ((size_t)blockIdx.x * 256 + threadIdx.x) * 8;
    int o = (int)(t8 & 255);
    int n = (int)((t8 >> 8) & 4095);
    int b = (int)(t8 >> 20);
    size_t si = (size_t)n * 2048 + b * 256 + o;
    bfx8 a = *(const bfx8*)&sA[si];
    bfx8 bb = *(const bfx8*)&sB[si];
    float d = dv_is[n];
    f32x4 v0, v1;
#pragma unroll
    for (int t = 0; t < 4; t++) {
        v0[t] = d * ((float)a[t] + (float)bb[t]);
        v1[t] = d * ((float)a[4 + t] + (float)bb[4 + t]);
    }
    *(f32x4*)&out[t8] = v0;
    *(f32x4*)&out[t8 + 4] = v1;
}

// ---------------------------------------------------------------------------
extern "C" void kernel_launch(void* const* d_in, const int* in_sizes, int n_in,
                              void* d_out, int out_size, void* d_ws, size_t ws_size,
                              hipStream_t stream) {
    const float* x    = (const float*)d_in[0];  // [8,4096,256]
    const float* ew   = (const float*)d_in[1];  // [2048]
    const float* H    = (const float*)d_in[2];  // [4096,2048]
    const float* W    = (const float*)d_in[3];  // [256,256]
    const float* bias = (const float*)d_in[4];  // [256]

    const int N = 4096, E = 2048;

    // ws (<= 42.0 MB, same proven footprint as previous version):
    char* ws = (char*)d_ws;
    float* de    = (float*)(ws);               // 2048 f32
    float* dvr   = (float*)(ws + 8192);        // 4096 f32
    float* dv_is = (float*)(ws + 24576);       // 4096 f32
    float* wsc   = (float*)(ws + 40960);       // 2048 f32
    bf16*  HT    = (bf16*)(ws + 65536);                // [E][N] 16 MB (dead after transpose)
    bf16*  xs_t  = (bf16*)(ws + 65536 + 16777216);     // [2048][4096] 16 MB (dead after K4)
    bf16*  t_t   = (bf16*)(ws + 65536 + 33554432);     // [2048][2048]  8 MB

    // d_out (32 MiB) scratch timeline:
    //  K4:        s0..s3 = 4 x 8MB bf16 split-K slices (whole d_out)
    //  transpose: Hb = bf16 H [n][e] 16 MB @ d_out[0:16M) (slices dead)
    //  K5:        reads Hb; writes its 2 slices into HT/xs_t slots (dead)
    //  combine:   final f32 out overwrites everything (Hb dead by then)
    bf16* s0 = (bf16*)d_out;
    bf16* s1 = s0 + 4194304;
    bf16* s2 = s0 + 2 * 4194304;
    bf16* s3 = s0 + 3 * 4194304;
    bf16* Hb = (bf16*)d_out;
    bf16* k5a = HT;    // K5 slice 0 (HT slot, dead)
    bf16* k5b = xs_t;  // K5 slice 1 (xs_t slot, dead)

    (void)hipMemsetAsync(ws, 0, 24576, stream);  // de + dvr

    prep_kernel<<<dim3(E / 64, N / 64), 256, 0, stream>>>(H, ew, HT, de, dvr, N, E);
    finalize_kernel<<<dim3(16), 256, 0, stream>>>(dvr, de, ew, dv_is, wsc, N, E);

    // K3: xs_t[b*256+o][n] = (sum_d W[o][d]*x[b][n][d] + bias[o]) * dv_is[n]
    gemm_bt_conv<<<dim3(4096 / BM, 256 / BM, 8), 256, 0, stream>>>(
        W, x, 256, xs_t, 4096, bias, dv_is, 1048576LL, 1048576LL);

    // K4 split-K=4: s[z][c][e] = sum_{n in z-quarter} xs_t[c][n] * HT[e][n]
    // grid 8x8x4 = 256 blocks (1/CU, 8 waves), kLen=1024 -> NT=16
    gemm8ph<<<dim3(8, 8, 4), 512, 0, stream>>>(xs_t, HT, 4096, 1024, s0, s1, s2, s3, 2048);

    // t_t = bf16((s0+s1+s2+s3) * wsc[e])
    combine4_kernel<<<dim3(2048), 256, 0, stream>>>(s0, s1, s2, s3, wsc, t_t);

    // Hb[n][e] = HT[e][n]^T  (replaces old D2D memcpy; slices now dead)
    transpose_kernel<<<dim3(64, 32), 256, 0, stream>>>(HT, Hb, 2048, 4096);

    // K5 split-K=2: slice[z][n][c] = sum_{e in z-half} Hb[n][e] * t_t[c][e]
    // grid 8x16x2 = 256 blocks, kLen=1024 -> NT=16
    gemm8ph<<<dim3(8, 16, 2), 512, 0, stream>>>(Hb, t_t, 2048, 1024, k5a, k5b, k5a, k5a, 2048);

    // out[b][n][o] = dv_is[n] * (k5a + k5b)
    combine_out_kernel<<<dim3(4096), 256, 0, stream>>>(k5a, k5b, dv_is, (float*)d_out);
}